// Round 2
// baseline (813293.848 us; speedup 1.0000x reference)
//
#include <hip/hip_runtime.h>

// ---------------------------------------------------------------------------
// WaveRNN forward on MI355X — T-chunked pipeline (fits any ws_size).
// Only cross-t dependency is the GRU recurrences -> chunk T=11000 into C-step
// slices; carry h (8x512) between GRU chunk launches. Flag targets are
// monotone across launches (single 16KB flag buffer, memset once per call).
//   per chunk: mup -> xi_in -> GEMM xi -> GEMM xW1 -> GRU1 -> xr1=xi+h1
//              -> GEMM xW2 -> GRU2 -> xr2=xr1+h2 -> fc1 -> fc2 -> fc3
// Per-chunk ws = 21120*C floats + ~4MB fixed. C picked from ws_size.
// ---------------------------------------------------------------------------

#define TT   11000
#define HH   512
#define NB_  8
#define NWGB 16                 // workgroups per batch element
#define JPW  (HH/NWGB)          // 32 h-outputs per WG
#define GROWS (3*JPW)           // 96 weight rows per WG
#define TPR  8                  // threads per row
#define GRU_THREADS (GROWS*TPR) // 768
#define KSL  (HH/TPR)           // 64 weights per thread (in VGPRs)
#define FLS  32                 // flag stride in uints (128B)

// ---------------- front-end (tiny, run once) ----------------

__global__ __launch_bounds__(256) void conv_in_kernel(
    const float* __restrict__ mels, const float* __restrict__ w,
    const float* __restrict__ s, const float* __restrict__ bb,
    const float* __restrict__ m, const float* __restrict__ v,
    float* __restrict__ out)
{
    int idx = blockIdx.x * 256 + threadIdx.x;
    if (idx >= 8*128*40) return;
    int t = idx % 40;
    int o = (idx / 40) % 128;
    int b = idx / (40*128);
    float acc = 0.f;
    for (int c = 0; c < 80; c++) {
        const float* mp = mels + ((size_t)b*80 + c)*44 + t;
        const float* wp = w + ((size_t)o*80 + c)*5;
        #pragma unroll
        for (int k = 0; k < 5; k++) acc += mp[k] * wp[k];
    }
    float inv = s[o] * rsqrtf(v[o] + 1e-5f);
    float val = (acc - m[o]) * inv + bb[o];
    out[idx] = fmaxf(val, 0.f);
}

template<int RELU, int ADDIN>
__global__ __launch_bounds__(256) void conv1x1_bn_kernel(
    const float* __restrict__ xin, const float* __restrict__ w,
    const float* __restrict__ s, const float* __restrict__ bb,
    const float* __restrict__ m, const float* __restrict__ v,
    const float* __restrict__ addin, float* __restrict__ out)
{
    int idx = blockIdx.x * 256 + threadIdx.x;
    if (idx >= 8*128*40) return;
    int t = idx % 40;
    int o = (idx / 40) % 128;
    int b = idx / (40*128);
    const float* xb = xin + (size_t)b*128*40 + t;
    const float* wo = w + (size_t)o*128;
    float acc = 0.f;
    #pragma unroll 4
    for (int c = 0; c < 128; c++) acc += xb[(size_t)c*40] * wo[c];
    float inv = s[o] * rsqrtf(v[o] + 1e-5f);
    float val = (acc - m[o]) * inv + bb[o];
    if (RELU) val = fmaxf(val, 0.f);
    if (ADDIN) val += addin[idx];
    out[idx] = val;
}

__global__ __launch_bounds__(256) void conv_out_kernel(
    const float* __restrict__ xin, const float* __restrict__ w,
    const float* __restrict__ bias, float* __restrict__ out)
{
    int idx = blockIdx.x * 256 + threadIdx.x;
    if (idx >= 8*128*40) return;
    int t = idx % 40;
    int o = (idx / 40) % 128;
    int b = idx / (40*128);
    const float* xb = xin + (size_t)b*128*40 + t;
    const float* wo = w + (size_t)o*128;
    float acc = 0.f;
    #pragma unroll 4
    for (int c = 0; c < 128; c++) acc += xb[(size_t)c*40] * wo[c];
    out[idx] = acc + bias[o];
}

// repeat(s) + conv(Kw, pad=s): out[t] = sum_k in[(t+k-s)/s]*w[k], zero OOB
__global__ __launch_bounds__(256) void upsample_stage_kernel(
    const float* __restrict__ in, float* __restrict__ out,
    int Tin, int s, int Kw, const float* __restrict__ w)
{
    int Tout = Tin * s;
    int total = 8*80*Tout;
    int idx = blockIdx.x * 256 + threadIdx.x;
    if (idx >= total) return;
    int t  = idx % Tout;
    int bc = idx / Tout;
    const float* ip = in + (size_t)bc * Tin;
    float acc = 0.f;
    for (int k = 0; k < Kw; k++) {
        int u = t + k - s;
        if (u >= 0 && u < Tout) acc += ip[u / s] * w[k];
    }
    out[idx] = acc;
}

// last stage (s=11,Kw=23) fused with crop(+550) + transpose, chunked over t
__global__ __launch_bounds__(256) void upsample_final_kernel(
    const float* __restrict__ c1, float* __restrict__ mup,
    const float* __restrict__ w, int C, int t0)
{
    int idx = blockIdx.x * 256 + threadIdx.x;
    if (idx >= 8*C*80) return;
    int c  = idx % 80;
    int tl = (idx / 80) % C;
    int b  = idx / (80*C);
    int tt = t0 + tl + 550;
    const float* ip = c1 + ((size_t)b*80 + c)*1100;
    float acc = 0.f;
    #pragma unroll
    for (int k = 0; k < 23; k++) {
        int u = tt + k - 11;               // always within [0,12100)
        acc += ip[u / 11] * w[k];
    }
    mup[idx] = acc;
}

// xi_in[b*C+tl][k] = concat(x(1), m_up(80), a1(32), spk(256)); K=369
__global__ __launch_bounds__(256) void build_xi_in_kernel(
    const float* __restrict__ x, const float* __restrict__ mup,
    const float* __restrict__ auxf, const float* __restrict__ spk,
    float* __restrict__ xi_in, int C, int t0)
{
    size_t idx = (size_t)blockIdx.x * 256 + threadIdx.x;
    if (idx >= (size_t)8 * C * 369) return;
    int k   = (int)(idx % 369);
    int btc = (int)(idx / 369);
    int b  = btc / C;
    int tl = btc % C;
    int tg = t0 + tl;
    float val;
    if (k == 0)        val = x[(size_t)b*TT + tg];
    else if (k < 81)   val = mup[(size_t)btc*80 + (k-1)];
    else if (k < 113)  val = auxf[((size_t)b*128 + (k-81))*40 + (tg/275)];
    else               val = spk[(size_t)b*256 + (k-113)];
    xi_in[idx] = val;
}

__global__ __launch_bounds__(256) void add_inplace_kernel(
    float4* __restrict__ x, const float4* __restrict__ y)
{
    size_t idx = (size_t)blockIdx.x * 256 + threadIdx.x;  // grid sized exactly
    float4 a = x[idx], b = y[idx];
    a.x += b.x; a.y += b.y; a.z += b.z; a.w += b.w;
    x[idx] = a;
}

// ---------------- fp32 GEMM: C = act(A_cat @ Bw^T + bias) -------------------
// A compact [M][lda] (M=8*Trows rows = (b,tl)). k in [KA,Ktot) gathers
// auxf[b][auxc0+(k-KA)][(t0+tl)/275]. Output row = b*outT + out_t0 + tl.
template<int RELU>
__global__ __launch_bounds__(256) void gemm_kernel(
    const float* __restrict__ A, int lda, int KA, int Ktot,
    const float* __restrict__ Bw, const float* __restrict__ bias,
    float* __restrict__ Cc, int N, int Trows, int M, int outT, int out_t0,
    const float* __restrict__ auxf, int auxc0, int t0)
{
    __shared__ float As[16][68];   // [k][m], +4 pad
    __shared__ float Bs[16][68];   // [k][n]
    const int m0 = blockIdx.y * 64;
    const int n0 = blockIdx.x * 64;
    const int tid = threadIdx.x;
    const int r = tid >> 2;        // 0..63 staging row
    const int q = tid & 3;         // 0..3 staging k-quad
    const int tm = tid & 15;
    const int tn = tid >> 4;

    const int am   = m0 + r;
    const int amc  = (am < M) ? am : (M-1);
    const bool amok = (am < M);
    const int ab   = amc / Trows;
    const int atl  = amc % Trows;
    const int afr  = (t0 + atl) / 275;
    const int bn   = n0 + r;

    float acc[4][4] = {};
    float areg[4], breg[4];
    const int nk = (Ktot + 15) / 16;

    auto loadA = [&](int k0) {
        #pragma unroll
        for (int e = 0; e < 4; e++) {
            int kk = k0 + q*4 + e;
            float v = 0.f;
            if (amok) {
                if (kk < KA)        v = A[(size_t)am * lda + kk];
                else if (kk < Ktot) v = auxf[((size_t)ab*128 + (auxc0 + kk - KA))*40 + afr];
            }
            areg[e] = v;
        }
    };
    auto loadB = [&](int k0) {
        #pragma unroll
        for (int e = 0; e < 4; e++) {
            int kk = k0 + q*4 + e;
            breg[e] = (kk < Ktot) ? Bw[(size_t)bn * Ktot + kk] : 0.f;
        }
    };

    loadA(0); loadB(0);

    for (int kt = 0; kt < nk; kt++) {
        #pragma unroll
        for (int e = 0; e < 4; e++) {
            As[q*4 + e][r] = areg[e];
            Bs[q*4 + e][r] = breg[e];
        }
        __syncthreads();
        if (kt + 1 < nk) { loadA((kt+1)*16); loadB((kt+1)*16); }  // hide latency
        #pragma unroll
        for (int k = 0; k < 16; k++) {
            float av[4], bv[4];
            *(float4*)av = *(const float4*)&As[k][tm*4];
            *(float4*)bv = *(const float4*)&Bs[k][tn*4];
            #pragma unroll
            for (int ii = 0; ii < 4; ii++)
                #pragma unroll
                for (int jj = 0; jj < 4; jj++)
                    acc[ii][jj] += av[ii] * bv[jj];
        }
        __syncthreads();
    }

    #pragma unroll
    for (int ii = 0; ii < 4; ii++) {
        int m = m0 + tm*4 + ii;
        if (m >= M) continue;
        int orow = (m / Trows) * outT + out_t0 + (m % Trows);
        float4 o4;
        float* op = &o4.x;
        #pragma unroll
        for (int jj = 0; jj < 4; jj++) {
            float v = acc[ii][jj] + bias[n0 + tn*4 + jj];
            if (RELU) v = fmaxf(v, 0.f);
            op[jj] = v;
        }
        *(float4*)&Cc[(size_t)orow * N + n0 + tn*4] = o4;
    }
}

// ---------------- persistent GRU kernel (one T-chunk) ----------------
// 16 WGs per batch element; WG w owns h-outputs [32w,32w+32), weight rows
// {j,512+j,1024+j} in registers (64 fp32/thread, 8 threads/row). Cross-WG
// step sync: agent-scope h stores + per-WG monotone flags (tbase+t+1).
__global__ __launch_bounds__(GRU_THREADS, 1) void gru_kernel(
    const float* __restrict__ xW,     // [8][Tc][1536]
    const float* __restrict__ wh,     // [1536][512]
    const float* __restrict__ bh,     // [1536]
    float* __restrict__ h_hist,       // [8][Tc][512]
    const float* __restrict__ h_init, // [8][512] carry in
    float* __restrict__ h_fin,        // [8][512] carry out
    unsigned int* __restrict__ flags, int Tc, unsigned int tbase)
{
    const int b  = blockIdx.x & 7;     // blockIdx%8==b -> same-XCD grouping
    const int w  = blockIdx.x >> 3;
    const int tid = threadIdx.x;
    const int i  = tid / TPR;          // local row 0..95
    const int p  = tid % TPR;          // k-part 0..7
    const int g  = i / JPW;            // gate 0..2
    const int jj = i % JPW;
    const int grow = g*HH + w*JPW + jj;

    __shared__ float h_lds[HH + TPR*4];   // k stored at k+(k>>6)*4
    __shared__ float gh_lds[GROWS];

    float4 wreg[KSL/4];
    {
        const float* wp = wh + (size_t)grow * HH + p * KSL;
        #pragma unroll
        for (int qq = 0; qq < KSL/4; qq++)
            wreg[qq] = ((const float4*)wp)[qq];
    }

    float bh_r = 0.f, bh_z = 0.f, bh_n = 0.f;
    if (tid < JPW) {
        int j = w*JPW + tid;
        bh_r = bh[j]; bh_z = bh[HH + j]; bh_n = bh[2*HH + j];
    }

    const size_t xw_base = (size_t)b * Tc * (3*HH);
    const size_t h_base  = (size_t)b * Tc * HH;
    unsigned int* fl = flags + (size_t)b * NWGB * FLS;
    const int lane = tid & 63;
    const unsigned int* pollp = &fl[(lane & (NWGB-1)) * FLS];

    for (int t = 0; t < Tc; t++) {
        // prefetch this step's input-gate slice (overlaps the spin below)
        float xw_r = 0.f, xw_z = 0.f, xw_n = 0.f;
        if (tid < JPW) {
            const float* xp = xW + xw_base + (size_t)t*(3*HH) + w*JPW + tid;
            xw_r = xp[0]; xw_z = xp[HH]; xw_n = xp[2*HH];
        }
        if (t > 0) {
            unsigned tgt = tbase + (unsigned)t;
            while (true) {
                unsigned vv = __hip_atomic_load(pollp, __ATOMIC_ACQUIRE,
                                                __HIP_MEMORY_SCOPE_AGENT);
                if (__all((int)(vv >= tgt))) break;
            }
            __builtin_amdgcn_fence(__ATOMIC_ACQUIRE, "agent");
        }
        // stage h(t-1) into LDS
        if (tid < HH) {
            float hv;
            if (t > 0)
                hv = __hip_atomic_load(&h_hist[h_base + (size_t)(t-1)*HH + tid],
                                       __ATOMIC_RELAXED, __HIP_MEMORY_SCOPE_AGENT);
            else
                hv = h_init[(size_t)b*HH + tid];
            h_lds[tid + ((tid >> 6) << 2)] = hv;
        }
        __syncthreads();

        // gh[row]: 64 reg-weights x LDS h slice, 8-thread shuffle reduce
        const float4* hp = (const float4*)&h_lds[p * (KSL + 4)];
        float4 a = {0.f, 0.f, 0.f, 0.f};
        #pragma unroll
        for (int qq = 0; qq < KSL/4; qq++) {
            float4 h4 = hp[qq];
            a.x += wreg[qq].x * h4.x;
            a.y += wreg[qq].y * h4.y;
            a.z += wreg[qq].z * h4.z;
            a.w += wreg[qq].w * h4.w;
        }
        float sum = (a.x + a.y) + (a.z + a.w);
        sum += __shfl_down(sum, 4, 8);
        sum += __shfl_down(sum, 2, 8);
        sum += __shfl_down(sum, 1, 8);
        if (p == 0) gh_lds[i] = sum;
        __syncthreads();

        if (tid < JPW) {
            int j = w*JPW + tid;
            float ghr = gh_lds[tid]         + bh_r;
            float ghz = gh_lds[JPW + tid]   + bh_z;
            float ghn = gh_lds[2*JPW + tid] + bh_n;
            float r = 1.f / (1.f + expf(-(xw_r + ghr)));
            float z = 1.f / (1.f + expf(-(xw_z + ghz)));
            float n = tanhf(xw_n + r * ghn);
            float hold = h_lds[j + ((j >> 6) << 2)];
            float hnew = (1.f - z) * n + z * hold;
            __hip_atomic_store(&h_hist[h_base + (size_t)t*HH + j], hnew,
                               __ATOMIC_RELAXED, __HIP_MEMORY_SCOPE_AGENT);
            if (t == Tc - 1) h_fin[(size_t)b*HH + j] = hnew;
        }
        __syncthreads();   // barrier drains all threads' stores (vmcnt 0)
        if (tid == 0) {
            __builtin_amdgcn_fence(__ATOMIC_RELEASE, "agent");
            __hip_atomic_store(&fl[w * FLS], tbase + (unsigned)(t + 1),
                               __ATOMIC_RELEASE, __HIP_MEMORY_SCOPE_AGENT);
        }
    }
}

// ---------------------------------------------------------------------------

extern "C" void kernel_launch(void* const* d_in, const int* in_sizes, int n_in,
                              void* d_out, int out_size, void* d_ws, size_t ws_size,
                              hipStream_t stream)
{
    const float* x         = (const float*)d_in[0];
    const float* mels      = (const float*)d_in[1];
    const float* spk       = (const float*)d_in[2];
    const float* conv_in_w = (const float*)d_in[3];
    const float* bn_in_s   = (const float*)d_in[4];
    const float* bn_in_b   = (const float*)d_in[5];
    const float* bn_in_m   = (const float*)d_in[6];
    const float* bn_in_v   = (const float*)d_in[7];
    const float* res_c1_w  = (const float*)d_in[8];
    const float* res_bn1_s = (const float*)d_in[9];
    const float* res_bn1_b = (const float*)d_in[10];
    const float* res_bn1_m = (const float*)d_in[11];
    const float* res_bn1_v = (const float*)d_in[12];
    const float* res_c2_w  = (const float*)d_in[13];
    const float* res_bn2_s = (const float*)d_in[14];
    const float* res_bn2_b = (const float*)d_in[15];
    const float* res_bn2_m = (const float*)d_in[16];
    const float* res_bn2_v = (const float*)d_in[17];
    const float* conv_out_w= (const float*)d_in[18];
    const float* conv_out_b= (const float*)d_in[19];
    const float* up_w0     = (const float*)d_in[20];
    const float* up_w1     = (const float*)d_in[21];
    const float* up_w2     = (const float*)d_in[22];
    const float* I_w       = (const float*)d_in[23];
    const float* I_b       = (const float*)d_in[24];
    const float* gru1_wi   = (const float*)d_in[25];
    const float* gru1_bi   = (const float*)d_in[27];
    const float* gru1_wh   = (const float*)d_in[26];
    const float* gru1_bh   = (const float*)d_in[28];
    const float* gru2_wi   = (const float*)d_in[29];
    const float* gru2_wh   = (const float*)d_in[30];
    const float* gru2_bi   = (const float*)d_in[31];
    const float* gru2_bh   = (const float*)d_in[32];
    const float* fc1_w     = (const float*)d_in[33];
    const float* fc1_b     = (const float*)d_in[34];
    const float* fc2_w     = (const float*)d_in[35];
    const float* fc2_b     = (const float*)d_in[36];
    const float* fc3_w     = (const float*)d_in[37];
    const float* fc3_b     = (const float*)d_in[38];
    float* out = (float*)d_out;

    // ---- pick largest T-chunk C (divisor of 11000) fitting ws_size ----
    static const int cands[] = {2200, 1000, 440, 200, 88, 40, 8};
    const size_t fixedF = 979968 + 1024;          // small bufs + slack (floats)
    int C = 8;
    for (int ci = 0; ci < 7; ci++) {
        size_t need = ((size_t)21120 * cands[ci] + fixedF) * 4;
        if (need <= ws_size) { C = cands[ci]; break; }
    }
    const int nch = TT / C;
    const int M   = 8 * C;

    float* ws = (float*)d_ws;
    float* xw_buf = ws;                      // 12288*C (also xi_in / f1 / f2)
    float* xi_buf = ws + (size_t)12288*C;    // 4096*C  (xi -> xr1 -> xr2)
    float* h_buf  = ws + (size_t)16384*C;    // 4096*C  (h1 then h2)
    float* mup    = ws + (size_t)20480*C;    // 640*C
    float* c0     = ws + (size_t)21120*C;    // 140800
    float* c1     = c0 + 140800;             // 704000
    float* h0     = c1 + 704000;             // 40960
    float* t1b    = h0 + 40960;              // 40960
    float* auxf   = t1b + 40960;             // 40960
    float* hc1    = auxf + 40960;            // 4096
    float* hc2    = hc1 + 4096;              // 4096
    unsigned int* flags = (unsigned int*)(hc2 + 4096);  // 4096 uints
    float* xi_in = xw_buf;                   // 2952*C, dead before xW1 GEMM
    float* f1    = xw_buf;                   // 4096*C
    float* f2    = xw_buf + (size_t)4096*C;  // 4096*C

    // zero h-carries + flags (contiguous 12288 floats = 48KB)
    hipMemsetAsync(hc1, 0, 12288 * sizeof(float), stream);

    // ---- frontend (once) ----
    conv_in_kernel<<<160, 256, 0, stream>>>(mels, conv_in_w, bn_in_s, bn_in_b,
                                            bn_in_m, bn_in_v, h0);
    for (int i = 0; i < 10; i++) {
        conv1x1_bn_kernel<1,0><<<160, 256, 0, stream>>>(
            h0, res_c1_w + (size_t)i*128*128,
            res_bn1_s + i*128, res_bn1_b + i*128, res_bn1_m + i*128, res_bn1_v + i*128,
            nullptr, t1b);
        conv1x1_bn_kernel<0,1><<<160, 256, 0, stream>>>(
            t1b, res_c2_w + (size_t)i*128*128,
            res_bn2_s + i*128, res_bn2_b + i*128, res_bn2_m + i*128, res_bn2_v + i*128,
            h0, h0);
    }
    conv_out_kernel<<<160, 256, 0, stream>>>(h0, conv_out_w, conv_out_b, auxf);
    upsample_stage_kernel<<<(8*80*220 + 255)/256, 256, 0, stream>>>(mels, c0, 44, 5, 11, up_w0);
    upsample_stage_kernel<<<(8*80*1100 + 255)/256, 256, 0, stream>>>(c0, c1, 220, 5, 11, up_w1);

    // ---- chunked pipeline ----
    const int My = (M + 63) / 64;
    dim3 g512(8, My), g1536(24, My);
    unsigned int tbase = 0;
    for (int ci = 0; ci < nch; ci++) {
        const int t0 = ci * C;

        upsample_final_kernel<<<(8*C*80 + 255)/256, 256, 0, stream>>>(c1, mup, up_w2, C, t0);
        build_xi_in_kernel<<<(int)(((size_t)8*C*369 + 255)/256), 256, 0, stream>>>(
            x, mup, auxf, spk, xi_in, C, t0);

        gemm_kernel<0><<<g512, 256, 0, stream>>>(xi_in, 369, 369, 369, I_w, I_b,
            xi_buf, 512, C, M, C, 0, nullptr, 0, t0);
        gemm_kernel<0><<<g1536, 256, 0, stream>>>(xi_buf, 512, 512, 512, gru1_wi, gru1_bi,
            xw_buf, 1536, C, M, C, 0, nullptr, 0, t0);

        gru_kernel<<<NB_*NWGB, GRU_THREADS, 0, stream>>>(xw_buf, gru1_wh, gru1_bh,
            h_buf, hc1, hc1, flags, C, tbase);
        tbase += (unsigned)C;

        add_inplace_kernel<<<4*C, 256, 0, stream>>>((float4*)xi_buf, (const float4*)h_buf);
        gemm_kernel<0><<<g1536, 256, 0, stream>>>(xi_buf, 512, 512, 544, gru2_wi, gru2_bi,
            xw_buf, 1536, C, M, C, 0, auxf, 32, t0);

        gru_kernel<<<NB_*NWGB, GRU_THREADS, 0, stream>>>(xw_buf, gru2_wh, gru2_bh,
            h_buf, hc2, hc2, flags, C, tbase);
        tbase += (unsigned)C;

        add_inplace_kernel<<<4*C, 256, 0, stream>>>((float4*)xi_buf, (const float4*)h_buf);
        gemm_kernel<1><<<g512, 256, 0, stream>>>(xi_buf, 512, 512, 544, fc1_w, fc1_b,
            f1, 512, C, M, C, 0, auxf, 64, t0);
        gemm_kernel<1><<<g512, 256, 0, stream>>>(f1, 512, 512, 544, fc2_w, fc2_b,
            f2, 512, C, M, C, 0, auxf, 96, t0);
        gemm_kernel<0><<<g512, 256, 0, stream>>>(f2, 512, 512, 512, fc3_w, fc3_b,
            out, 512, C, M, TT, t0, nullptr, 0, t0);
    }
}

// Round 3
// 57172.681 us; speedup vs baseline: 14.2252x; 14.2252x over previous
//
#include <hip/hip_runtime.h>

// ---------------------------------------------------------------------------
// WaveRNN forward on MI355X — T-chunked pipeline (fits any ws_size).
// Only cross-t dependency is the GRU recurrences -> chunk T=11000 into C-step
// slices; carry h (8x512) between GRU chunk launches. Flag targets are
// monotone across launches (single flag buffer, memset once per call).
//   per chunk: mup -> xi_in -> GEMM xi -> GEMM xW1 -> GRU1 -> xr1=xi+h1
//              -> GEMM xW2 -> GRU2 -> xr2=xr1+h2 -> fc1 -> fc2 -> fc3
// R3 change: GRU cross-WG sync uses ONLY relaxed agent-scope atomics (sc1
// ops bypass the non-coherent L1/L2 -> no buffer_inv / buffer_wbl2 storms
// that made each step ~50us). Producer order: h stores -> s_waitcnt(0) ->
// barrier -> flag store. Consumer: wave0-only relaxed poll + wg acquire fence.
// ---------------------------------------------------------------------------

#define TT   11000
#define HH   512
#define NB_  8
#define NWGB 16                 // workgroups per batch element
#define JPW  (HH/NWGB)          // 32 h-outputs per WG
#define GROWS (3*JPW)           // 96 weight rows per WG
#define TPR  8                  // threads per row
#define GRU_THREADS (GROWS*TPR) // 768
#define KSL  (HH/TPR)           // 64 weights per thread (in VGPRs)
#define FLS  32                 // flag stride in uints (128B)

// ---------------- front-end (tiny, run once) ----------------

__global__ __launch_bounds__(256) void conv_in_kernel(
    const float* __restrict__ mels, const float* __restrict__ w,
    const float* __restrict__ s, const float* __restrict__ bb,
    const float* __restrict__ m, const float* __restrict__ v,
    float* __restrict__ out)
{
    int idx = blockIdx.x * 256 + threadIdx.x;
    if (idx >= 8*128*40) return;
    int t = idx % 40;
    int o = (idx / 40) % 128;
    int b = idx / (40*128);
    float acc = 0.f;
    for (int c = 0; c < 80; c++) {
        const float* mp = mels + ((size_t)b*80 + c)*44 + t;
        const float* wp = w + ((size_t)o*80 + c)*5;
        #pragma unroll
        for (int k = 0; k < 5; k++) acc += mp[k] * wp[k];
    }
    float inv = s[o] * rsqrtf(v[o] + 1e-5f);
    float val = (acc - m[o]) * inv + bb[o];
    out[idx] = fmaxf(val, 0.f);
}

template<int RELU, int ADDIN>
__global__ __launch_bounds__(256) void conv1x1_bn_kernel(
    const float* __restrict__ xin, const float* __restrict__ w,
    const float* __restrict__ s, const float* __restrict__ bb,
    const float* __restrict__ m, const float* __restrict__ v,
    const float* __restrict__ addin, float* __restrict__ out)
{
    int idx = blockIdx.x * 256 + threadIdx.x;
    if (idx >= 8*128*40) return;
    int t = idx % 40;
    int o = (idx / 40) % 128;
    int b = idx / (40*128);
    const float* xb = xin + (size_t)b*128*40 + t;
    const float* wo = w + (size_t)o*128;
    float acc = 0.f;
    #pragma unroll 4
    for (int c = 0; c < 128; c++) acc += xb[(size_t)c*40] * wo[c];
    float inv = s[o] * rsqrtf(v[o] + 1e-5f);
    float val = (acc - m[o]) * inv + bb[o];
    if (RELU) val = fmaxf(val, 0.f);
    if (ADDIN) val += addin[idx];
    out[idx] = val;
}

__global__ __launch_bounds__(256) void conv_out_kernel(
    const float* __restrict__ xin, const float* __restrict__ w,
    const float* __restrict__ bias, float* __restrict__ out)
{
    int idx = blockIdx.x * 256 + threadIdx.x;
    if (idx >= 8*128*40) return;
    int t = idx % 40;
    int o = (idx / 40) % 128;
    int b = idx / (40*128);
    const float* xb = xin + (size_t)b*128*40 + t;
    const float* wo = w + (size_t)o*128;
    float acc = 0.f;
    #pragma unroll 4
    for (int c = 0; c < 128; c++) acc += xb[(size_t)c*40] * wo[c];
    out[idx] = acc + bias[o];
}

// repeat(s) + conv(Kw, pad=s): out[t] = sum_k in[(t+k-s)/s]*w[k], zero OOB
__global__ __launch_bounds__(256) void upsample_stage_kernel(
    const float* __restrict__ in, float* __restrict__ out,
    int Tin, int s, int Kw, const float* __restrict__ w)
{
    int Tout = Tin * s;
    int total = 8*80*Tout;
    int idx = blockIdx.x * 256 + threadIdx.x;
    if (idx >= total) return;
    int t  = idx % Tout;
    int bc = idx / Tout;
    const float* ip = in + (size_t)bc * Tin;
    float acc = 0.f;
    for (int k = 0; k < Kw; k++) {
        int u = t + k - s;
        if (u >= 0 && u < Tout) acc += ip[u / s] * w[k];
    }
    out[idx] = acc;
}

// last stage (s=11,Kw=23) fused with crop(+550) + transpose, chunked over t
__global__ __launch_bounds__(256) void upsample_final_kernel(
    const float* __restrict__ c1, float* __restrict__ mup,
    const float* __restrict__ w, int C, int t0)
{
    int idx = blockIdx.x * 256 + threadIdx.x;
    if (idx >= 8*C*80) return;
    int c  = idx % 80;
    int tl = (idx / 80) % C;
    int b  = idx / (80*C);
    int tt = t0 + tl + 550;
    const float* ip = c1 + ((size_t)b*80 + c)*1100;
    float acc = 0.f;
    #pragma unroll
    for (int k = 0; k < 23; k++) {
        int u = tt + k - 11;               // always within [0,12100)
        acc += ip[u / 11] * w[k];
    }
    mup[idx] = acc;
}

// xi_in[b*C+tl][k] = concat(x(1), m_up(80), a1(32), spk(256)); K=369
__global__ __launch_bounds__(256) void build_xi_in_kernel(
    const float* __restrict__ x, const float* __restrict__ mup,
    const float* __restrict__ auxf, const float* __restrict__ spk,
    float* __restrict__ xi_in, int C, int t0)
{
    size_t idx = (size_t)blockIdx.x * 256 + threadIdx.x;
    if (idx >= (size_t)8 * C * 369) return;
    int k   = (int)(idx % 369);
    int btc = (int)(idx / 369);
    int b  = btc / C;
    int tl = btc % C;
    int tg = t0 + tl;
    float val;
    if (k == 0)        val = x[(size_t)b*TT + tg];
    else if (k < 81)   val = mup[(size_t)btc*80 + (k-1)];
    else if (k < 113)  val = auxf[((size_t)b*128 + (k-81))*40 + (tg/275)];
    else               val = spk[(size_t)b*256 + (k-113)];
    xi_in[idx] = val;
}

__global__ __launch_bounds__(256) void add_inplace_kernel(
    float4* __restrict__ x, const float4* __restrict__ y)
{
    size_t idx = (size_t)blockIdx.x * 256 + threadIdx.x;  // grid sized exactly
    float4 a = x[idx], b = y[idx];
    a.x += b.x; a.y += b.y; a.z += b.z; a.w += b.w;
    x[idx] = a;
}

// ---------------- fp32 GEMM: C = act(A_cat @ Bw^T + bias) -------------------
// A compact [M][lda] (M=8*Trows rows = (b,tl)). k in [KA,Ktot) gathers
// auxf[b][auxc0+(k-KA)][(t0+tl)/275]. Output row = b*outT + out_t0 + tl.
template<int RELU>
__global__ __launch_bounds__(256) void gemm_kernel(
    const float* __restrict__ A, int lda, int KA, int Ktot,
    const float* __restrict__ Bw, const float* __restrict__ bias,
    float* __restrict__ Cc, int N, int Trows, int M, int outT, int out_t0,
    const float* __restrict__ auxf, int auxc0, int t0)
{
    __shared__ float As[16][68];   // [k][m], +4 pad
    __shared__ float Bs[16][68];   // [k][n]
    const int m0 = blockIdx.y * 64;
    const int n0 = blockIdx.x * 64;
    const int tid = threadIdx.x;
    const int r = tid >> 2;        // 0..63 staging row
    const int q = tid & 3;         // 0..3 staging k-quad
    const int tm = tid & 15;
    const int tn = tid >> 4;

    const int am   = m0 + r;
    const int amc  = (am < M) ? am : (M-1);
    const bool amok = (am < M);
    const int ab   = amc / Trows;
    const int atl  = amc % Trows;
    const int afr  = (t0 + atl) / 275;
    const int bn   = n0 + r;

    float acc[4][4] = {};
    float areg[4], breg[4];
    const int nk = (Ktot + 15) / 16;

    auto loadA = [&](int k0) {
        #pragma unroll
        for (int e = 0; e < 4; e++) {
            int kk = k0 + q*4 + e;
            float v = 0.f;
            if (amok) {
                if (kk < KA)        v = A[(size_t)am * lda + kk];
                else if (kk < Ktot) v = auxf[((size_t)ab*128 + (auxc0 + kk - KA))*40 + afr];
            }
            areg[e] = v;
        }
    };
    auto loadB = [&](int k0) {
        #pragma unroll
        for (int e = 0; e < 4; e++) {
            int kk = k0 + q*4 + e;
            breg[e] = (kk < Ktot) ? Bw[(size_t)bn * Ktot + kk] : 0.f;
        }
    };

    loadA(0); loadB(0);

    for (int kt = 0; kt < nk; kt++) {
        #pragma unroll
        for (int e = 0; e < 4; e++) {
            As[q*4 + e][r] = areg[e];
            Bs[q*4 + e][r] = breg[e];
        }
        __syncthreads();
        if (kt + 1 < nk) { loadA((kt+1)*16); loadB((kt+1)*16); }  // hide latency
        #pragma unroll
        for (int k = 0; k < 16; k++) {
            float av[4], bv[4];
            *(float4*)av = *(const float4*)&As[k][tm*4];
            *(float4*)bv = *(const float4*)&Bs[k][tn*4];
            #pragma unroll
            for (int ii = 0; ii < 4; ii++)
                #pragma unroll
                for (int jj = 0; jj < 4; jj++)
                    acc[ii][jj] += av[ii] * bv[jj];
        }
        __syncthreads();
    }

    #pragma unroll
    for (int ii = 0; ii < 4; ii++) {
        int m = m0 + tm*4 + ii;
        if (m >= M) continue;
        int orow = (m / Trows) * outT + out_t0 + (m % Trows);
        float4 o4;
        float* op = &o4.x;
        #pragma unroll
        for (int jj = 0; jj < 4; jj++) {
            float v = acc[ii][jj] + bias[n0 + tn*4 + jj];
            if (RELU) v = fmaxf(v, 0.f);
            op[jj] = v;
        }
        *(float4*)&Cc[(size_t)orow * N + n0 + tn*4] = o4;
    }
}

// ---------------- persistent GRU kernel (one T-chunk) ----------------
// 16 WGs per batch element; WG w owns h-outputs [32w,32w+32), weight rows
// {j,512+j,1024+j} in registers (64 fp32/thread, 8 threads/row).
// Cross-WG step sync: ALL cross-WG traffic is relaxed agent-scope atomics
// (sc1 -> bypasses non-coherent L1/L2, meets at MALL). No acquire/release
// at agent scope anywhere (those lower to buffer_inv / buffer_wbl2 storms).
__global__ __launch_bounds__(GRU_THREADS, 1) void gru_kernel(
    const float* __restrict__ xW,     // [8][Tc][1536]
    const float* __restrict__ wh,     // [1536][512]
    const float* __restrict__ bh,     // [1536]
    float* __restrict__ h_hist,       // [8][Tc][512]
    const float* __restrict__ h_init, // [8][512] carry in
    float* __restrict__ h_fin,        // [8][512] carry out
    unsigned int* __restrict__ flags, int Tc, unsigned int tbase)
{
    const int b  = blockIdx.x & 7;
    const int w  = blockIdx.x >> 3;
    const int tid = threadIdx.x;
    const int i  = tid / TPR;          // local row 0..95
    const int p  = tid % TPR;          // k-part 0..7
    const int g  = i / JPW;            // gate 0..2
    const int jj = i % JPW;
    const int grow = g*HH + w*JPW + jj;

    __shared__ float h_lds[HH + TPR*4];   // k stored at k+(k>>6)*4
    __shared__ float gh_lds[GROWS];

    float4 wreg[KSL/4];
    {
        const float* wp = wh + (size_t)grow * HH + p * KSL;
        #pragma unroll
        for (int qq = 0; qq < KSL/4; qq++)
            wreg[qq] = ((const float4*)wp)[qq];
    }

    float bh_r = 0.f, bh_z = 0.f, bh_n = 0.f;
    if (tid < JPW) {
        int j = w*JPW + tid;
        bh_r = bh[j]; bh_z = bh[HH + j]; bh_n = bh[2*HH + j];
    }

    const size_t xw_base = (size_t)b * Tc * (3*HH);
    const size_t h_base  = (size_t)b * Tc * HH;
    unsigned int* fl = flags + (size_t)b * NWGB * FLS;
    const unsigned int* pollp = &fl[(tid & (NWGB-1)) * FLS];

    for (int t = 0; t < Tc; t++) {
        // prefetch this step's input-gate slice (no cross-WG dependency)
        float xw_r = 0.f, xw_z = 0.f, xw_n = 0.f;
        if (tid < JPW) {
            const float* xp = xW + xw_base + (size_t)t*(3*HH) + w*JPW + tid;
            xw_r = xp[0]; xw_z = xp[HH]; xw_n = xp[2*HH];
        }
        // wave0-only relaxed poll (no buffer_inv; other waves park at barrier)
        if (t > 0) {
            if (tid < 64) {
                unsigned tgt = tbase + (unsigned)t;
                while (true) {
                    unsigned vv = __hip_atomic_load(pollp, __ATOMIC_RELAXED,
                                                    __HIP_MEMORY_SCOPE_AGENT);
                    if (__all((int)(vv >= tgt))) break;
                }
            }
            __builtin_amdgcn_fence(__ATOMIC_ACQUIRE, "workgroup"); // compile-order only
            __syncthreads();
        }
        // stage h(t-1) into LDS (relaxed sc1 loads -> fresh from MALL)
        if (tid < HH) {
            float hv;
            if (t > 0)
                hv = __hip_atomic_load(&h_hist[h_base + (size_t)(t-1)*HH + tid],
                                       __ATOMIC_RELAXED, __HIP_MEMORY_SCOPE_AGENT);
            else
                hv = h_init[(size_t)b*HH + tid];
            h_lds[tid + ((tid >> 6) << 2)] = hv;
        }
        __syncthreads();

        // gh[row]: 64 reg-weights x LDS h slice, 8-thread shuffle reduce
        const float4* hp = (const float4*)&h_lds[p * (KSL + 4)];
        float4 a = {0.f, 0.f, 0.f, 0.f};
        #pragma unroll
        for (int qq = 0; qq < KSL/4; qq++) {
            float4 h4 = hp[qq];
            a.x += wreg[qq].x * h4.x;
            a.y += wreg[qq].y * h4.y;
            a.z += wreg[qq].z * h4.z;
            a.w += wreg[qq].w * h4.w;
        }
        float sum = (a.x + a.y) + (a.z + a.w);
        sum += __shfl_down(sum, 4, 8);
        sum += __shfl_down(sum, 2, 8);
        sum += __shfl_down(sum, 1, 8);
        if (p == 0) gh_lds[i] = sum;
        __syncthreads();

        if (tid < JPW) {
            int j = w*JPW + tid;
            float ghr = gh_lds[tid]         + bh_r;
            float ghz = gh_lds[JPW + tid]   + bh_z;
            float ghn = gh_lds[2*JPW + tid] + bh_n;
            float r = 1.f / (1.f + expf(-(xw_r + ghr)));
            float z = 1.f / (1.f + expf(-(xw_z + ghz)));
            float n = tanhf(xw_n + r * ghn);
            float hold = h_lds[j + ((j >> 6) << 2)];
            float hnew = (1.f - z) * n + z * hold;
            __hip_atomic_store(&h_hist[h_base + (size_t)t*HH + j], hnew,
                               __ATOMIC_RELAXED, __HIP_MEMORY_SCOPE_AGENT);
            if (t == Tc - 1) h_fin[(size_t)b*HH + j] = hnew;
        }
        // h stores must be complete-at-MALL before the flag store is issued:
        __builtin_amdgcn_s_waitcnt(0);   // vmcnt(0) lgkmcnt(0) expcnt(0)
        __syncthreads();
        if (tid == 0)
            __hip_atomic_store(&fl[w * FLS], tbase + (unsigned)(t + 1),
                               __ATOMIC_RELAXED, __HIP_MEMORY_SCOPE_AGENT);
    }
}

// ---------------------------------------------------------------------------

extern "C" void kernel_launch(void* const* d_in, const int* in_sizes, int n_in,
                              void* d_out, int out_size, void* d_ws, size_t ws_size,
                              hipStream_t stream)
{
    const float* x         = (const float*)d_in[0];
    const float* mels      = (const float*)d_in[1];
    const float* spk       = (const float*)d_in[2];
    const float* conv_in_w = (const float*)d_in[3];
    const float* bn_in_s   = (const float*)d_in[4];
    const float* bn_in_b   = (const float*)d_in[5];
    const float* bn_in_m   = (const float*)d_in[6];
    const float* bn_in_v   = (const float*)d_in[7];
    const float* res_c1_w  = (const float*)d_in[8];
    const float* res_bn1_s = (const float*)d_in[9];
    const float* res_bn1_b = (const float*)d_in[10];
    const float* res_bn1_m = (const float*)d_in[11];
    const float* res_bn1_v = (const float*)d_in[12];
    const float* res_c2_w  = (const float*)d_in[13];
    const float* res_bn2_s = (const float*)d_in[14];
    const float* res_bn2_b = (const float*)d_in[15];
    const float* res_bn2_m = (const float*)d_in[16];
    const float* res_bn2_v = (const float*)d_in[17];
    const float* conv_out_w= (const float*)d_in[18];
    const float* conv_out_b= (const float*)d_in[19];
    const float* up_w0     = (const float*)d_in[20];
    const float* up_w1     = (const float*)d_in[21];
    const float* up_w2     = (const float*)d_in[22];
    const float* I_w       = (const float*)d_in[23];
    const float* I_b       = (const float*)d_in[24];
    const float* gru1_wi   = (const float*)d_in[25];
    const float* gru1_wh   = (const float*)d_in[26];
    const float* gru1_bi   = (const float*)d_in[27];
    const float* gru1_bh   = (const float*)d_in[28];
    const float* gru2_wi   = (const float*)d_in[29];
    const float* gru2_wh   = (const float*)d_in[30];
    const float* gru2_bi   = (const float*)d_in[31];
    const float* gru2_bh   = (const float*)d_in[32];
    const float* fc1_w     = (const float*)d_in[33];
    const float* fc1_b     = (const float*)d_in[34];
    const float* fc2_w     = (const float*)d_in[35];
    const float* fc2_b     = (const float*)d_in[36];
    const float* fc3_w     = (const float*)d_in[37];
    const float* fc3_b     = (const float*)d_in[38];
    float* out = (float*)d_out;

    // ---- pick largest T-chunk C (divisor of 11000) fitting ws_size ----
    static const int cands[] = {2200, 1000, 440, 200, 88, 40, 8};
    const size_t fixedF = 979968 + 1024;          // small bufs + slack (floats)
    int C = 8;
    for (int ci = 0; ci < 7; ci++) {
        size_t need = ((size_t)21120 * cands[ci] + fixedF) * 4;
        if (need <= ws_size) { C = cands[ci]; break; }
    }
    const int nch = TT / C;
    const int M   = 8 * C;

    float* ws = (float*)d_ws;
    float* xw_buf = ws;                      // 12288*C (also xi_in / f1 / f2)
    float* xi_buf = ws + (size_t)12288*C;    // 4096*C  (xi -> xr1 -> xr2)
    float* h_buf  = ws + (size_t)16384*C;    // 4096*C  (h1 then h2)
    float* mup    = ws + (size_t)20480*C;    // 640*C
    float* c0     = ws + (size_t)21120*C;    // 140800
    float* c1     = c0 + 140800;             // 704000
    float* h0     = c1 + 704000;             // 40960
    float* t1b    = h0 + 40960;              // 40960
    float* auxf   = t1b + 40960;             // 40960
    float* hc1    = auxf + 40960;            // 4096
    float* hc2    = hc1 + 4096;              // 4096
    unsigned int* flags = (unsigned int*)(hc2 + 4096);  // 4096 uints
    float* xi_in = xw_buf;                   // 2952*C, dead before xW1 GEMM
    float* f1    = xw_buf;                   // 4096*C
    float* f2    = xw_buf + (size_t)4096*C;  // 4096*C

    // zero h-carries + flags (contiguous 12288 floats = 48KB)
    hipMemsetAsync(hc1, 0, 12288 * sizeof(float), stream);

    // ---- frontend (once) ----
    conv_in_kernel<<<160, 256, 0, stream>>>(mels, conv_in_w, bn_in_s, bn_in_b,
                                            bn_in_m, bn_in_v, h0);
    for (int i = 0; i < 10; i++) {
        conv1x1_bn_kernel<1,0><<<160, 256, 0, stream>>>(
            h0, res_c1_w + (size_t)i*128*128,
            res_bn1_s + i*128, res_bn1_b + i*128, res_bn1_m + i*128, res_bn1_v + i*128,
            nullptr, t1b);
        conv1x1_bn_kernel<0,1><<<160, 256, 0, stream>>>(
            t1b, res_c2_w + (size_t)i*128*128,
            res_bn2_s + i*128, res_bn2_b + i*128, res_bn2_m + i*128, res_bn2_v + i*128,
            h0, h0);
    }
    conv_out_kernel<<<160, 256, 0, stream>>>(h0, conv_out_w, conv_out_b, auxf);
    upsample_stage_kernel<<<(8*80*220 + 255)/256, 256, 0, stream>>>(mels, c0, 44, 5, 11, up_w0);
    upsample_stage_kernel<<<(8*80*1100 + 255)/256, 256, 0, stream>>>(c0, c1, 220, 5, 11, up_w1);

    // ---- chunked pipeline ----
    const int My = (M + 63) / 64;
    dim3 g512(8, My), g1536(24, My);
    unsigned int tbase = 0;
    for (int ci = 0; ci < nch; ci++) {
        const int t0 = ci * C;

        upsample_final_kernel<<<(8*C*80 + 255)/256, 256, 0, stream>>>(c1, mup, up_w2, C, t0);
        build_xi_in_kernel<<<(int)(((size_t)8*C*369 + 255)/256), 256, 0, stream>>>(
            x, mup, auxf, spk, xi_in, C, t0);

        gemm_kernel<0><<<g512, 256, 0, stream>>>(xi_in, 369, 369, 369, I_w, I_b,
            xi_buf, 512, C, M, C, 0, nullptr, 0, t0);
        gemm_kernel<0><<<g1536, 256, 0, stream>>>(xi_buf, 512, 512, 512, gru1_wi, gru1_bi,
            xw_buf, 1536, C, M, C, 0, nullptr, 0, t0);

        gru_kernel<<<NB_*NWGB, GRU_THREADS, 0, stream>>>(xw_buf, gru1_wh, gru1_bh,
            h_buf, hc1, hc1, flags, C, tbase);
        tbase += (unsigned)C;

        add_inplace_kernel<<<4*C, 256, 0, stream>>>((float4*)xi_buf, (const float4*)h_buf);
        gemm_kernel<0><<<g1536, 256, 0, stream>>>(xi_buf, 512, 512, 544, gru2_wi, gru2_bi,
            xw_buf, 1536, C, M, C, 0, auxf, 32, t0);

        gru_kernel<<<NB_*NWGB, GRU_THREADS, 0, stream>>>(xw_buf, gru2_wh, gru2_bh,
            h_buf, hc2, hc2, flags, C, tbase);
        tbase += (unsigned)C;

        add_inplace_kernel<<<4*C, 256, 0, stream>>>((float4*)xi_buf, (const float4*)h_buf);
        gemm_kernel<1><<<g512, 256, 0, stream>>>(xi_buf, 512, 512, 544, fc1_w, fc1_b,
            f1, 512, C, M, C, 0, auxf, 64, t0);
        gemm_kernel<1><<<g512, 256, 0, stream>>>(f1, 512, 512, 544, fc2_w, fc2_b,
            f2, 512, C, M, C, 0, auxf, 96, t0);
        gemm_kernel<0><<<g512, 256, 0, stream>>>(f2, 512, 512, 512, fc3_w, fc3_b,
            out, 512, C, M, TT, t0, nullptr, 0, t0);
    }
}